// Round 2
// baseline (883.723 us; speedup 1.0000x reference)
//
#include <hip/hip_runtime.h>
#include <stdint.h>

typedef __bf16 bf16;
typedef __bf16 bf16x8 __attribute__((ext_vector_type(8)));
typedef __bf16 bf16x4 __attribute__((ext_vector_type(4)));
typedef __bf16 bf16x2 __attribute__((ext_vector_type(2)));
typedef float  f32x4  __attribute__((ext_vector_type(4)));
typedef float  fvec4  __attribute__((ext_vector_type(4)));

// ---------------- workspace layout (bytes) ----------------
static const size_t OFF_A       = 0;         // 131072 f32 (per-token attn logit)
static const size_t OFF_SEGMAX  = 524288;    // 88 u32 (ordered-key max)
static const size_t OFF_DENOM   = 524800;    // 88 f32
static const size_t OFF_CNT     = 525312;    // 88 i32
static const size_t OFF_CFEAT   = 525824;    // 88*512 f32
static const size_t OFF_CFEAT2  = 706048;    // 88*512 f32
static const size_t ZERO_BYTES  = 886272;    // everything above zeroed each call
static const size_t OFF_FLAG    = 886272;    // 64 B (dtype flag)
static const size_t OFF_CANON   = 886336;    // 4096 bf16 canonical small params
static const size_t OFF_TEMB    = 894528;    // [11][512] f32 (emb tail + b_fuse)
static const size_t OFF_X       = 917056;    // 131072*512 bf16 = 128 MiB
static const size_t OFF_WFT     = OFF_X + (size_t)134217728;   // [512][512] bf16
static const size_t OFF_WGT     = OFF_WFT + 524288;            // [512][512] bf16 (Wa1/Wb1 16-col-group interleaved)
static const size_t OFF_WINTRAT = OFF_WGT + 524288;            // [512][512] bf16
static const size_t OFF_WA2T    = OFF_WINTRAT + 524288;        // [256][512] bf16
static const size_t OFF_WB2T    = OFF_WA2T + 262144;
static const size_t OFF_WINTERT = OFF_WB2T + 262144;           // [256][512] bf16

// canonical small-param offsets (bf16 elements within CANON)
#define CAN_BA1    0
#define CAN_BB1    256
#define CAN_WC1    512
#define CAN_BINTRA 768
#define CAN_BA2    1280
#define CAN_BB2    1536
#define CAN_WC2    1792
#define CAN_BINTER 2048
#define CAN_WCLS   2304
#define CAN_BCLS   2816

__device__ __forceinline__ int clip11(int c) { return c < 0 ? 0 : (c > 10 ? 10 : c); }

// NaN-PROPAGATING relu
__device__ __forceinline__ float relu_f(float v) { return v < 0.0f ? 0.0f : v; }

// fast tanh via hardware exp: saturates to +/-1, propagates NaN
__device__ __forceinline__ float fast_tanh(float a) {
  return 1.f - 2.f / (1.f + __expf(2.f * a));
}

__device__ __forceinline__ float cvt(const void* p, int i, int fl) {
  return fl ? ((const float*)p)[i] : (float)((const bf16*)p)[i];
}

__device__ __forceinline__ unsigned fkey(float f) {
  unsigned u = __float_as_uint(f);
  return (u & 0x80000000u) ? ~u : (u | 0x80000000u);
}
__device__ __forceinline__ float key_to_f(unsigned k) {
  unsigned u = (k & 0x80000000u) ? (k & 0x7FFFFFFFu) : ~k;
  return __uint_as_float(u);
}

__device__ __forceinline__ void async16(const void* g, void* l) {
  __builtin_amdgcn_global_load_lds(
      (const __attribute__((address_space(1))) unsigned int*)g,
      (__attribute__((address_space(3))) unsigned int*)l, 16, 0, 0);
}

// ---- 2-phase GEMM staging, BK=32 (rows of 32 bf16 = 64 B = 4 x 16B slots) ----
// Swizzle: phys slot p of row r holds global slot p ^ ((r>>1)&3).  Verified
// <=2-way per quarter-wave on reads (free) with ds_read_b128 at slot
// quad ^ ((l15>>1)&3).  global_load_lds writes linearly, so the swizzle is
// applied by permuting the per-lane GLOBAL source slot (both-sides rule).
// NT=512 threads, 8 waves; each round stages 128 rows (wave w: rows w*16..+15).
template <int ROWS>
__device__ __forceinline__ void stage32(const bf16* __restrict__ src, bf16* lds,
                                        int lane, int wid) {
#pragma unroll
  for (int j = 0; j < ROWS; j += 128) {
    const int row = j + wid * 16 + (lane >> 2);
    const int gs  = (lane & 3) ^ ((row >> 1) & 3);
    async16(src + (size_t)row * 512 + gs * 8, lds + (j + wid * 16) * 32);
  }
}

// f32 A-path: register-staged (load early / convert+ds_write late)
struct AF32 { fvec4 v0, v1; };
__device__ __forceinline__ AF32 load_a_f32(const float* __restrict__ g, int tid) {
  const int row = tid >> 2;                       // 128 rows, 4 thr/row
  const int gs  = (tid & 3) ^ ((row >> 1) & 3);   // inverse swizzle on source
  const float* gp = g + (size_t)row * 512 + gs * 8;
  AF32 r; r.v0 = *(const fvec4*)gp; r.v1 = *(const fvec4*)(gp + 4);
  return r;
}
__device__ __forceinline__ void store_a_f32(const AF32& r, bf16* lds, int tid) {
  const int row = tid >> 2;
  bf16x8 b;
  b[0]=(bf16)r.v0[0]; b[1]=(bf16)r.v0[1]; b[2]=(bf16)r.v0[2]; b[3]=(bf16)r.v0[3];
  b[4]=(bf16)r.v1[0]; b[5]=(bf16)r.v1[1]; b[6]=(bf16)r.v1[2]; b[7]=(bf16)r.v1[3];
  *(bf16x8*)(lds + row * 32 + (tid & 3) * 8) = b;   // linear phys slot
}

// ============ dtype detector ============
__global__ void k_detect(const unsigned short* __restrict__ hh, int* __restrict__ flag) {
  const int lane = threadIdx.x;  // 64 lanes
  const unsigned short u = hh[lane * 2];
  const int e = (u >> 7) & 0xFF;
  int pl = (e > 96 && e < 140) ? 1 : 0;
#pragma unroll
  for (int off = 1; off < 64; off <<= 1) pl += __shfl_xor(pl, off, 64);
  if (lane == 0) *flag = (pl < 32) ? 1 : 0;
}

// ============ kernel 1: x = relu(h @ Wfuse + T[cid]) ============
// 2-phase pipelined GEMM: block = 128 tokens x 256 cols, 512 threads (8 waves
// 2m x 4n, wave tile 64x64, acc[4][4]).  BK=32 double-buffered (48 KB LDS ->
// 2 blocks/CU, 16 waves/CU).  Prefetch of tile t+1 issued BEFORE compute of
// tile t; single __syncthreads per phase.
__global__ __launch_bounds__(512, 4) void k_fuse(
    const void* __restrict__ h, const int* __restrict__ cids,
    const bf16* __restrict__ WfT, const float* __restrict__ Temb,
    const int* __restrict__ flag, bf16* __restrict__ x) {
  __shared__ __align__(16) bf16 As[2][128 * 32];   // 16 KB
  __shared__ __align__(16) bf16 Bs[2][256 * 32];   // 32 KB
  const int tid = threadIdx.x, lane = tid & 63, wid = tid >> 6;
  const int quad = lane >> 4, l15 = lane & 15;
  const int mchunk = blockIdx.x >> 1, nb = blockIdx.x & 1;
  const int m0 = mchunk * 128, n0 = nb * 256;
  const int fl = *flag;
  const int wm = (wid >> 2) * 64, wc = wid & 3;
  const int so = ((quad ^ ((l15 >> 1) & 3)) << 3);  // swizzled read slot (bf16 elems)

  const bf16*  hb   = (const bf16*)h + (size_t)m0 * 512;
  const float* hf   = (const float*)h + (size_t)m0 * 512;
  const bf16*  Bsrc = WfT + (size_t)n0 * 512;

  f32x4 acc[4][4] = {};
  // prologue: stage tile 0
  if (fl) { AF32 a0 = load_a_f32(hf, tid); store_a_f32(a0, As[0], tid); }
  else    stage32<128>(hb, As[0], lane, wid);
  stage32<256>(Bsrc, Bs[0], lane, wid);
  __syncthreads();

  int buf = 0;
  for (int t = 0; t < 16; ++t) {
    AF32 ahold;
    const bool pf = (t < 15);
    if (pf) {  // issue next-tile staging FIRST (overlaps with compute below)
      const int k0 = (t + 1) * 32;
      if (fl) ahold = load_a_f32(hf + k0, tid);
      else    stage32<128>(hb + k0, As[buf ^ 1], lane, wid);
      stage32<256>(Bsrc + k0, Bs[buf ^ 1], lane, wid);
    }
    bf16x8 af[4], bfr[4];
#pragma unroll
    for (int tt = 0; tt < 4; ++tt)
      af[tt] = *(const bf16x8*)&As[buf][(wm + tt * 16 + l15) * 32 + so];
#pragma unroll
    for (int tt = 0; tt < 4; ++tt)
      bfr[tt] = *(const bf16x8*)&Bs[buf][(wc * 64 + tt * 16 + l15) * 32 + so];
#pragma unroll
    for (int tm = 0; tm < 4; ++tm)
#pragma unroll
      for (int tn = 0; tn < 4; ++tn)
        acc[tm][tn] = __builtin_amdgcn_mfma_f32_16x16x32_bf16(af[tm], bfr[tn], acc[tm][tn], 0, 0, 0);
    if (pf && fl) store_a_f32(ahold, As[buf ^ 1], tid);
    if (pf) __syncthreads();
    buf ^= 1;
  }
  // epilogue: + Temb[cid] bias, relu, bf16 store
#pragma unroll
  for (int tm = 0; tm < 4; ++tm) {
#pragma unroll
    for (int r = 0; r < 4; ++r) {
      const int m = m0 + wm + tm * 16 + quad * 4 + r;
      const int c = clip11(cids[m]);
      const float* Trow = Temb + c * 512;
#pragma unroll
      for (int tn = 0; tn < 4; ++tn) {
        const int nn = n0 + wc * 64 + tn * 16 + l15;
        x[(size_t)m * 512 + nn] = (bf16)relu_f(acc[tm][tn][r] + Trow[nn]);
      }
    }
  }
}

// ============ kernel 2: per-token gate logit ============
// Same 2-phase structure.  WgT 16-col-group interleave: col n with (n>>4)&1==0
// = tanh side of dim d, ==1 = sigmoid side of same d; acc[tm][2p]/[2p+1] in the
// same lane form the (a,g) pair, d = nb*128 + wc*32 + p*16 + l15.
// Per-token partial sums accumulated via global atomicAdd (Apart pre-zeroed).
__global__ __launch_bounds__(512, 4) void k_gate1(
    const bf16* __restrict__ x, const bf16* __restrict__ WgT,
    const bf16* __restrict__ canon, float* __restrict__ Apart) {
  __shared__ __align__(16) bf16 As[2][128 * 32];
  __shared__ __align__(16) bf16 Bs[2][256 * 32];
  const int tid = threadIdx.x, lane = tid & 63, wid = tid >> 6;
  const int quad = lane >> 4, l15 = lane & 15;
  const int mchunk = blockIdx.x >> 1, nb = blockIdx.x & 1;
  const int m0 = mchunk * 128, n0 = nb * 256;
  const int wm = (wid >> 2) * 64, wc = wid & 3;
  const int so = ((quad ^ ((l15 >> 1) & 3)) << 3);

  const bf16* Asrc = x + (size_t)m0 * 512;
  const bf16* Bsrc = WgT + (size_t)n0 * 512;

  f32x4 acc[4][4] = {};
  stage32<128>(Asrc, As[0], lane, wid);
  stage32<256>(Bsrc, Bs[0], lane, wid);
  __syncthreads();

  int buf = 0;
  for (int t = 0; t < 16; ++t) {
    const bool pf = (t < 15);
    if (pf) {
      const int k0 = (t + 1) * 32;
      stage32<128>(Asrc + k0, As[buf ^ 1], lane, wid);
      stage32<256>(Bsrc + k0, Bs[buf ^ 1], lane, wid);
    }
    bf16x8 af[4], bfr[4];
#pragma unroll
    for (int tt = 0; tt < 4; ++tt)
      af[tt] = *(const bf16x8*)&As[buf][(wm + tt * 16 + l15) * 32 + so];
#pragma unroll
    for (int tt = 0; tt < 4; ++tt)
      bfr[tt] = *(const bf16x8*)&Bs[buf][(wc * 64 + tt * 16 + l15) * 32 + so];
#pragma unroll
    for (int tm = 0; tm < 4; ++tm)
#pragma unroll
      for (int tn = 0; tn < 4; ++tn)
        acc[tm][tn] = __builtin_amdgcn_mfma_f32_16x16x32_bf16(af[tm], bfr[tn], acc[tm][tn], 0, 0, 0);
    if (pf) __syncthreads();
    buf ^= 1;
  }
  // epilogue: gated-attention logit, reduce over this block's 64-col wave slice
  float bav[2], bbv[2], wcv[2];
  const int dbase = nb * 128 + wc * 32;
#pragma unroll
  for (int p = 0; p < 2; ++p) {
    const int d = dbase + p * 16 + l15;
    bav[p] = (float)canon[CAN_BA1 + d];
    bbv[p] = (float)canon[CAN_BB1 + d];
    wcv[p] = (float)canon[CAN_WC1 + d];
  }
#pragma unroll
  for (int tm = 0; tm < 4; ++tm) {
#pragma unroll
    for (int r = 0; r < 4; ++r) {
      float rs = 0.f;
#pragma unroll
      for (int p = 0; p < 2; ++p) {
        const float a = acc[tm][2 * p][r] + bav[p];
        const float g = acc[tm][2 * p + 1][r] + bbv[p];
        rs += fast_tanh(a) * (1.f / (1.f + __expf(-g))) * wcv[p];
      }
      rs += __shfl_xor(rs, 1, 64);
      rs += __shfl_xor(rs, 2, 64);
      rs += __shfl_xor(rs, 4, 64);
      rs += __shfl_xor(rs, 8, 64);
      if (l15 == 0) atomicAdd(&Apart[m0 + wm + tm * 16 + quad * 4 + r], rs);
    }
  }
}

// ============ kernel 3a: per-segment max ============
__global__ __launch_bounds__(256) void k_segmax(
    const float* __restrict__ Apart, const int* __restrict__ cids, unsigned* __restrict__ gmax) {
  __shared__ unsigned sm[88];
  const int tid = threadIdx.x;
  if (tid < 88) sm[tid] = 0u;
  __syncthreads();
  const int base = blockIdx.x * 1024;
  const int b = blockIdx.x >> 4;
#pragma unroll
  for (int it = 0; it < 4; ++it) {
    const int t = base + it * 256 + tid;
    atomicMax(&sm[b * 11 + clip11(cids[t])], fkey(Apart[t]));
  }
  __syncthreads();
  if (tid < 88) atomicMax(&gmax[tid], sm[tid]);
}

// ============ kernel 3b: per-segment sum of exp + counts ============
__global__ __launch_bounds__(256) void k_segsum(
    const float* __restrict__ Apart, const int* __restrict__ cids,
    const unsigned* __restrict__ gmax, float* __restrict__ denom, int* __restrict__ counts) {
  __shared__ float sd[88];
  __shared__ int sc[88];
  const int tid = threadIdx.x;
  if (tid < 88) { sd[tid] = 0.f; sc[tid] = 0; }
  __syncthreads();
  const int base = blockIdx.x * 1024;
  const int b = blockIdx.x >> 4;
#pragma unroll
  for (int it = 0; it < 4; ++it) {
    const int t = base + it * 256 + tid;
    const int seg = b * 11 + clip11(cids[t]);
    atomicAdd(&sd[seg], __expf(Apart[t] - key_to_f(gmax[seg])));
    atomicAdd(&sc[seg], 1);
  }
  __syncthreads();
  if (tid < 88) {
    atomicAdd(&denom[tid], sd[tid]);
    atomicAdd(&counts[tid], sc[tid]);
  }
}

// ============ kernel 3c: cfeat[seg] += w * x[token] (full 512 cols, bf16x2) ============
__global__ __launch_bounds__(256) void k_cfeat(
    const float* __restrict__ Apart, const int* __restrict__ cids,
    const unsigned* __restrict__ gmax, const float* __restrict__ denom,
    const bf16* __restrict__ x, float* __restrict__ cfeat) {
  __shared__ float accf[11 * 512];      // 22.5 KB
  __shared__ float wbuf[512];
  __shared__ unsigned char cbuf[512];
  const int tid = threadIdx.x;
  const int base = blockIdx.x * 512;    // 256 blocks x 512 tokens
  const int b = blockIdx.x >> 5;        // 32 blocks per batch
  for (int i = tid; i < 11 * 512; i += 256) accf[i] = 0.f;
#pragma unroll
  for (int it = 0; it < 2; ++it) {
    const int t = base + it * 256 + tid;
    const int c = clip11(cids[t]);
    const int seg = b * 11 + c;
    wbuf[it * 256 + tid] = __expf(Apart[t] - key_to_f(gmax[seg])) / denom[seg];
    cbuf[it * 256 + tid] = (unsigned char)c;
  }
  __syncthreads();
  const bf16* xp = x + (size_t)base * 512 + tid * 2;
#pragma unroll 4
  for (int i = 0; i < 512; ++i) {
    const float w = wbuf[i];
    const int c = cbuf[i];
    bf16x2 v = *(const bf16x2*)(xp + (size_t)i * 512);
    accf[c * 512 + tid * 2]     += w * (float)v[0];
    accf[c * 512 + tid * 2 + 1] += w * (float)v[1];
  }
  __syncthreads();
  float* cf = cfeat + (size_t)b * 11 * 512;
  for (int i = tid; i < 11 * 512; i += 256)
    atomicAdd(&cf[i], accf[i]);
}

// ============ kernel 4a: cfeat2 = relu(cfeat @ Wintra + b_intra), 88 rows ============
__global__ __launch_bounds__(256) void k_intra(
    const float* __restrict__ cfeat, const bf16* __restrict__ WintraT,
    const bf16* __restrict__ canon, float* __restrict__ cfeat2) {
  __shared__ float row[512];
  const int r = blockIdx.x, tid = threadIdx.x;
  row[tid] = cfeat[(size_t)r * 512 + tid];
  row[tid + 256] = cfeat[(size_t)r * 512 + 256 + tid];
  __syncthreads();
#pragma unroll
  for (int hh = 0; hh < 2; ++hh) {
    const int n = hh * 256 + tid;
    float acc = (float)canon[CAN_BINTRA + n];
    const bf16* wp = WintraT + (size_t)n * 512;
    for (int k = 0; k < 512; k += 8) {
      bf16x8 wv = *(const bf16x8*)(wp + k);
#pragma unroll
      for (int j = 0; j < 8; ++j) acc += row[k + j] * (float)wv[j];
    }
    cfeat2[(size_t)r * 512 + n] = relu_f(acc);
  }
}

__device__ __forceinline__ float block_sum(float v, float* red, int tid) {
#pragma unroll
  for (int off = 32; off > 0; off >>= 1) v += __shfl_xor(v, off, 64);
  __syncthreads();
  if ((tid & 63) == 0) red[tid >> 6] = v;
  __syncthreads();
  return red[0] + red[1] + red[2] + red[3];
}

// ============ kernel 4b: inter-cluster attention + classifier ============
__global__ __launch_bounds__(256) void k_tail(
    const float* __restrict__ cfeat2, const int* __restrict__ counts,
    const bf16* __restrict__ Wa2T, const bf16* __restrict__ Wb2T,
    const bf16* __restrict__ WinterT, const bf16* __restrict__ canon,
    const int* __restrict__ flag, void* __restrict__ out) {
  const int b = blockIdx.x, tid = threadIdx.x;
  __shared__ float row[512];
  __shared__ float A2[11], Wsm[11];
  __shared__ float red[4];
  __shared__ float slide[512];
  __shared__ float hid[256];
  const float* cf = cfeat2 + (size_t)b * 11 * 512;

  for (int c = 0; c < 11; ++c) {
    row[tid] = cf[c * 512 + tid];
    row[tid + 256] = cf[c * 512 + 256 + tid];
    __syncthreads();
    float da = (float)canon[CAN_BA2 + tid], dg = (float)canon[CAN_BB2 + tid];
    const bf16* wa = Wa2T + (size_t)tid * 512;
    const bf16* wb = Wb2T + (size_t)tid * 512;
    for (int k = 0; k < 512; k += 8) {
      bf16x8 av = *(const bf16x8*)(wa + k);
      bf16x8 gv = *(const bf16x8*)(wb + k);
#pragma unroll
      for (int j = 0; j < 8; ++j) {
        const float rv = row[k + j];
        da += rv * (float)av[j];
        dg += rv * (float)gv[j];
      }
    }
    const float contrib = fast_tanh(da) * (1.f / (1.f + __expf(-dg))) * (float)canon[CAN_WC2 + tid];
    const float tot = block_sum(contrib, red, tid);
    if (tid == 0) A2[c] = tot;
    __syncthreads();
  }
  if (tid == 0) {
    float mx = -1e30f;
    for (int c = 0; c < 11; ++c)
      if (counts[b * 11 + c] > 0 && A2[c] > mx) mx = A2[c];
    float s = 0.f;
    for (int c = 0; c < 11; ++c) {
      const float e = (counts[b * 11 + c] > 0) ? __expf(A2[c] - mx) : 0.f;
      Wsm[c] = e; s += e;
    }
    for (int c = 0; c < 11; ++c) Wsm[c] /= s;
  }
  __syncthreads();
  float s0 = 0.f, s1 = 0.f;
  for (int c = 0; c < 11; ++c) {
    const float w = Wsm[c];
    s0 += w * cf[c * 512 + tid];
    s1 += w * cf[c * 512 + 256 + tid];
  }
  slide[tid] = s0; slide[tid + 256] = s1;
  __syncthreads();
  {
    float acc = (float)canon[CAN_BINTER + tid];
    const bf16* wp = WinterT + (size_t)tid * 512;
    for (int k = 0; k < 512; k += 8) {
      bf16x8 wv = *(const bf16x8*)(wp + k);
#pragma unroll
      for (int j = 0; j < 8; ++j) acc += slide[k + j] * (float)wv[j];
    }
    hid[tid] = relu_f(acc);
  }
  __syncthreads();
  const float p0 = hid[tid] * (float)canon[CAN_WCLS + tid * 2 + 0];
  const float p1 = hid[tid] * (float)canon[CAN_WCLS + tid * 2 + 1];
  const float t0 = block_sum(p0, red, tid);
  const float t1 = block_sum(p1, red, tid);
  if (tid == 0) {
    const float o0 = t0 + (float)canon[CAN_BCLS + 0];
    const float o1 = t1 + (float)canon[CAN_BCLS + 1];
    if (*flag) {
      ((float*)out)[b * 2 + 0] = o0;
      ((float*)out)[b * 2 + 1] = o1;
    } else {
      ((bf16*)out)[b * 2 + 0] = (bf16)o0;
      ((bf16*)out)[b * 2 + 1] = (bf16)o1;
    }
  }
}

// ============ prep: transposes + interleaved gate weight + canon + emb-tail ============
__global__ __launch_bounds__(256) void k_prep(
    const void* __restrict__ Wf, const void* __restrict__ bfuse, const void* __restrict__ emb,
    const void* __restrict__ Wa1, const void* __restrict__ Wb1, const void* __restrict__ Wintra,
    const void* __restrict__ Wa2, const void* __restrict__ Wb2, const void* __restrict__ Winter,
    const void* __restrict__ ba1, const void* __restrict__ bb1, const void* __restrict__ wc1,
    const void* __restrict__ bintra, const void* __restrict__ ba2, const void* __restrict__ bb2,
    const void* __restrict__ wc2, const void* __restrict__ binter, const void* __restrict__ Wcls,
    const void* __restrict__ bcls, const int* __restrict__ flag,
    bf16* __restrict__ WfT, bf16* __restrict__ WgT,
    bf16* __restrict__ WintraT, bf16* __restrict__ Wa2T, bf16* __restrict__ Wb2T,
    bf16* __restrict__ WinterT, float* __restrict__ Temb, bf16* __restrict__ canon) {
  const int fl = *flag;
  int id = blockIdx.x * 256 + threadIdx.x;
  if (id < 262144) { WfT[id] = (bf16)cvt(Wf, (id & 511) * 512 + (id >> 9), fl); return; }
  id -= 262144;
  if (id < 262144) {
    // WgT row r (= output col): 16-col-group interleave.
    // q = r>>5 selects d-group, (r>>4)&1 selects side (0=tanh/Wa1, 1=sigmoid/Wb1),
    // d = q*16 + (r&15).
    const int r = id >> 9, k = id & 511;
    const int d = ((r >> 5) << 4) | (r & 15);
    WgT[id] = (bf16)cvt(((r >> 4) & 1) ? Wb1 : Wa1, k * 256 + d, fl);
    return;
  }
  id -= 262144;
  if (id < 262144) { WintraT[id] = (bf16)cvt(Wintra, (id & 511) * 512 + (id >> 9), fl); return; }
  id -= 262144;
  if (id < 131072) { Wa2T[id] = (bf16)cvt(Wa2, (id & 511) * 256 + (id >> 9), fl); return; }
  id -= 131072;
  if (id < 131072) { Wb2T[id] = (bf16)cvt(Wb2, (id & 511) * 256 + (id >> 9), fl); return; }
  id -= 131072;
  if (id < 131072) { WinterT[id] = (bf16)cvt(Winter, (id & 511) * 256 + (id >> 9), fl); return; }
  id -= 131072;
  if (id < 5632) {
    const int c = id >> 9, n = id & 511;
    float s = cvt(bfuse, n, fl);
#pragma unroll
    for (int j = 0; j < 8; ++j) s += cvt(emb, c * 8 + j, fl) * cvt(Wf, (512 + j) * 512 + n, fl);
    Temb[id] = s;
    return;
  }
  id -= 5632;
  if (id < 4096) {
    bf16 v = (bf16)0.0f;
    if (id < 256)        v = (bf16)cvt(ba1, id, fl);
    else if (id < 512)   v = (bf16)cvt(bb1, id - 256, fl);
    else if (id < 768)   v = (bf16)cvt(wc1, id - 512, fl);
    else if (id < 1280)  v = (bf16)cvt(bintra, id - 768, fl);
    else if (id < 1536)  v = (bf16)cvt(ba2, id - 1280, fl);
    else if (id < 1792)  v = (bf16)cvt(bb2, id - 1536, fl);
    else if (id < 2048)  v = (bf16)cvt(wc2, id - 1792, fl);
    else if (id < 2304)  v = (bf16)cvt(binter, id - 2048, fl);
    else if (id < 2816)  v = (bf16)cvt(Wcls, id - 2304, fl);
    else if (id < 2818)  v = (bf16)cvt(bcls, id - 2816, fl);
    canon[id] = v;
  }
}

extern "C" void kernel_launch(void* const* d_in, const int* in_sizes, int n_in,
                              void* d_out, int out_size, void* d_ws, size_t ws_size,
                              hipStream_t stream) {
  (void)in_sizes; (void)n_in; (void)out_size; (void)ws_size;
  const void* h      = d_in[0];
  const int*  cids   = (const int*)d_in[1];
  const void* emb    = d_in[2];
  const void* Wf     = d_in[3];
  const void* bfuse  = d_in[4];
  const void* Wa1    = d_in[5];
  const void* ba1    = d_in[6];
  const void* Wb1    = d_in[7];
  const void* bb1    = d_in[8];
  const void* wc1    = d_in[9];
  const void* Wintra = d_in[11];
  const void* bintra = d_in[12];
  const void* Wa2    = d_in[13];
  const void* ba2    = d_in[14];
  const void* Wb2    = d_in[15];
  const void* bb2    = d_in[16];
  const void* wc2    = d_in[17];
  const void* Winter = d_in[19];
  const void* binter = d_in[20];
  const void* Wcls   = d_in[21];
  const void* bcls   = d_in[22];

  char* ws = (char*)d_ws;
  float*    Apart   = (float*)(ws + OFF_A);
  unsigned* gmax    = (unsigned*)(ws + OFF_SEGMAX);
  float*    denom   = (float*)(ws + OFF_DENOM);
  int*      counts  = (int*)(ws + OFF_CNT);
  float*    cfeat   = (float*)(ws + OFF_CFEAT);
  float*    cfeat2  = (float*)(ws + OFF_CFEAT2);
  int*      flag    = (int*)(ws + OFF_FLAG);
  bf16*     canon   = (bf16*)(ws + OFF_CANON);
  float*    Temb    = (float*)(ws + OFF_TEMB);
  bf16*     x       = (bf16*)(ws + OFF_X);
  bf16*     WfT     = (bf16*)(ws + OFF_WFT);
  bf16*     WgT     = (bf16*)(ws + OFF_WGT);
  bf16*     WintraT = (bf16*)(ws + OFF_WINTRAT);
  bf16*     Wa2T    = (bf16*)(ws + OFF_WA2T);
  bf16*     Wb2T    = (bf16*)(ws + OFF_WB2T);
  bf16*     WinterT = (bf16*)(ws + OFF_WINTERT);

  hipMemsetAsync(d_ws, 0, ZERO_BYTES, stream);
  k_detect<<<1, 64, 0, stream>>>((const unsigned short*)h, flag);
  k_prep<<<4646, 256, 0, stream>>>(Wf, bfuse, emb, Wa1, Wb1, Wintra, Wa2, Wb2, Winter,
                                   ba1, bb1, wc1, bintra, ba2, bb2, wc2, binter, Wcls, bcls,
                                   flag, WfT, WgT, WintraT, Wa2T, Wb2T, WinterT, Temb, canon);
  k_fuse<<<2048, 512, 0, stream>>>(h, cids, WfT, Temb, flag, x);
  k_gate1<<<2048, 512, 0, stream>>>(x, WgT, canon, Apart);
  k_segmax<<<128, 256, 0, stream>>>(Apart, cids, gmax);
  k_segsum<<<128, 256, 0, stream>>>(Apart, cids, gmax, denom, counts);
  k_cfeat<<<256, 256, 0, stream>>>(Apart, cids, gmax, denom, x, cfeat);
  k_intra<<<88, 256, 0, stream>>>(cfeat, WintraT, canon, cfeat2);
  k_tail<<<8, 256, 0, stream>>>(cfeat2, counts, Wa2T, Wb2T, WinterT, canon, flag, d_out);
}

// Round 3
// 863.421 us; speedup vs baseline: 1.0235x; 1.0235x over previous
//
#include <hip/hip_runtime.h>
#include <stdint.h>

typedef __bf16 bf16;
typedef __bf16 bf16x8 __attribute__((ext_vector_type(8)));
typedef __bf16 bf16x4 __attribute__((ext_vector_type(4)));
typedef __bf16 bf16x2 __attribute__((ext_vector_type(2)));
typedef float  f32x4  __attribute__((ext_vector_type(4)));
typedef float  fvec4  __attribute__((ext_vector_type(4)));

// ---------------- workspace layout (bytes) ----------------
static const size_t OFF_A       = 0;         // 131072 f32 (per-token attn logit)
static const size_t OFF_SEGMAX  = 524288;    // 88 u32 (ordered-key max)
static const size_t OFF_DENOM   = 524800;    // 88 f32
static const size_t OFF_CNT     = 525312;    // 88 i32
static const size_t OFF_CFEAT   = 525824;    // 88*512 f32
static const size_t OFF_CFEAT2  = 706048;    // 88*512 f32
static const size_t ZERO_BYTES  = 886272;    // everything above zeroed each call
static const size_t OFF_FLAG    = 886272;    // 64 B (dtype flag)
static const size_t OFF_CANON   = 886336;    // 4096 bf16 canonical small params
static const size_t OFF_TEMB    = 894528;    // [11][512] f32 (emb tail + b_fuse)
static const size_t OFF_X       = 917056;    // 131072*512 bf16 = 128 MiB
static const size_t OFF_WFT     = OFF_X + (size_t)134217728;   // [512][512] bf16
static const size_t OFF_WGT     = OFF_WFT + 524288;            // [512][512] bf16 (Wa1/Wb1 16-col-group interleaved)
static const size_t OFF_WINTRAT = OFF_WGT + 524288;            // [512][512] bf16
static const size_t OFF_WA2T    = OFF_WINTRAT + 524288;        // [256][512] bf16
static const size_t OFF_WB2T    = OFF_WA2T + 262144;
static const size_t OFF_WINTERT = OFF_WB2T + 262144;           // [256][512] bf16

// canonical small-param offsets (bf16 elements within CANON)
#define CAN_BA1    0
#define CAN_BB1    256
#define CAN_WC1    512
#define CAN_BINTRA 768
#define CAN_BA2    1280
#define CAN_BB2    1536
#define CAN_WC2    1792
#define CAN_BINTER 2048
#define CAN_WCLS   2304
#define CAN_BCLS   2816

__device__ __forceinline__ int clip11(int c) { return c < 0 ? 0 : (c > 10 ? 10 : c); }

// NaN-PROPAGATING relu
__device__ __forceinline__ float relu_f(float v) { return v < 0.0f ? 0.0f : v; }

// fast tanh via hardware exp: saturates to +/-1, propagates NaN
__device__ __forceinline__ float fast_tanh(float a) {
  return 1.f - 2.f / (1.f + __expf(2.f * a));
}

__device__ __forceinline__ float cvt(const void* p, int i, int fl) {
  return fl ? ((const float*)p)[i] : (float)((const bf16*)p)[i];
}

__device__ __forceinline__ unsigned fkey(float f) {
  unsigned u = __float_as_uint(f);
  return (u & 0x80000000u) ? ~u : (u | 0x80000000u);
}
__device__ __forceinline__ float key_to_f(unsigned k) {
  unsigned u = (k & 0x80000000u) ? (k & 0x7FFFFFFFu) : ~k;
  return __uint_as_float(u);
}

__device__ __forceinline__ void async16(const void* g, void* l) {
  __builtin_amdgcn_global_load_lds(
      (const __attribute__((address_space(1))) unsigned int*)g,
      (__attribute__((address_space(3))) unsigned int*)l, 16, 0, 0);
}

#define VMCNT(n)  asm volatile("s_waitcnt vmcnt(" #n ")" ::: "memory")
#define LGKMCNT0  asm volatile("s_waitcnt lgkmcnt(0)" ::: "memory")
#define SBAR      __builtin_amdgcn_s_barrier()

// ---- GEMM tile: 64 tokens x 512 cols, 256 threads (4 waves), BK=32 ----
// LDS rows are 32 bf16 = 64 B = 4 x 16B slots.  Swizzle: phys slot p of row r
// holds global slot p ^ ((r>>1)&3) (round-2 verified: 0 bank conflicts).
// global_load_lds writes linearly -> swizzle applied on the GLOBAL source slot.

// B staging: 512 rows x 32, 8 async16 per thread (counts toward vmcnt).
__device__ __forceinline__ void stageB512(const bf16* __restrict__ src, bf16* lds,
                                          int lane, int wid) {
#pragma unroll
  for (int j = 0; j < 512; j += 64) {
    const int row = j + wid * 16 + (lane >> 2);
    const int gs  = (lane & 3) ^ ((row >> 1) & 3);
    async16(src + (size_t)row * 512 + gs * 8, lds + (j + wid * 16) * 32);
  }
}

// A register-staging: 64 rows x 32 (one bf16 slot of 8 elems per thread).
// Exactly 2 vmem loads per thread for BOTH f32 and bf16 sources (vmcnt parity).
struct AHold { fvec4 v0, v1; bf16x4 b0, b1; };
__device__ __forceinline__ void loadA(AHold& h, const void* __restrict__ src, int fl,
                                      size_t m0, int k0, int tid) {
  const int row = tid >> 2, slot = tid & 3;
  const int gs  = slot ^ ((row >> 1) & 3);
  if (fl) {
    const float* gp = (const float*)src + (m0 + row) * 512 + k0 + gs * 8;
    h.v0 = *(const fvec4*)gp;
    h.v1 = *(const fvec4*)(gp + 4);
  } else {
    const bf16* gp = (const bf16*)src + (m0 + row) * 512 + k0 + gs * 8;
    h.b0 = *(const bf16x4*)gp;
    h.b1 = *(const bf16x4*)(gp + 4);
  }
}
__device__ __forceinline__ void writeA(const AHold& h, bf16* lds, int fl, int tid) {
  const int row = tid >> 2, slot = tid & 3;
  bf16x8 b;
  if (fl) {
    b[0]=(bf16)h.v0[0]; b[1]=(bf16)h.v0[1]; b[2]=(bf16)h.v0[2]; b[3]=(bf16)h.v0[3];
    b[4]=(bf16)h.v1[0]; b[5]=(bf16)h.v1[1]; b[6]=(bf16)h.v1[2]; b[7]=(bf16)h.v1[3];
  } else {
    b[0]=h.b0[0]; b[1]=h.b0[1]; b[2]=h.b0[2]; b[3]=h.b0[3];
    b[4]=h.b1[0]; b[5]=h.b1[1]; b[6]=h.b1[2]; b[7]=h.b1[3];
  }
  *(bf16x8*)(lds + row * 32 + slot * 8) = b;   // linear phys slot (source pre-swizzled)
}

// ============ dtype detector ============
__global__ void k_detect(const unsigned short* __restrict__ hh, int* __restrict__ flag) {
  const int lane = threadIdx.x;  // 64 lanes
  const unsigned short u = hh[lane * 2];
  const int e = (u >> 7) & 0xFF;
  int pl = (e > 96 && e < 140) ? 1 : 0;
#pragma unroll
  for (int off = 1; off < 64; off <<= 1) pl += __shfl_xor(pl, off, 64);
  if (lane == 0) *flag = (pl < 32) ? 1 : 0;
}

// Counted-vmcnt double-buffered K-loop (T4).  Per phase/thread: A=2 loads
// (reg-staged), B=8 global_load_lds.  Steady state keeps 10 vmem in flight
// across the barriers; vmcnt never drains to 0 inside the loop.
// Ledger: barrier_A (post-compute) protects LDS buffers being overwritten;
// vmcnt(8) retires A(t+1) before its ds_write; vmcnt(10) retires B(t+1);
// LGKMCNT0 makes the ds_write visible; barrier_B releases compute(t+1).
#define GEMM_PIPE(ASRC, FL, BSRC)                                              \
  {                                                                            \
    AHold ah;                                                                  \
    loadA(ah, ASRC, FL, m0, 0, tid);                                           \
    stageB512(BSRC, Bs[0], lane, wid);                                         \
    VMCNT(8);                                                                  \
    writeA(ah, As[0], FL, tid);                                                \
    loadA(ah, ASRC, FL, m0, 32, tid);                                          \
    stageB512(BSRC + 32, Bs[1], lane, wid);                                    \
    VMCNT(10);                                                                 \
    LGKMCNT0;                                                                  \
    SBAR;                                                                      \
    for (int t = 0; t < 16; ++t) {                                             \
      const int c = t & 1;                                                     \
      bf16x8 af[4], bfr[8];                                                    \
      _Pragma("unroll")                                                        \
      for (int tt = 0; tt < 4; ++tt)                                           \
        af[tt] = *(const bf16x8*)&As[c][(tt * 16 + l15) * 32 + so];            \
      _Pragma("unroll")                                                        \
      for (int tt = 0; tt < 8; ++tt)                                           \
        bfr[tt] = *(const bf16x8*)&Bs[c][(wid * 128 + tt * 16 + l15) * 32 + so];\
      _Pragma("unroll")                                                        \
      for (int tm = 0; tm < 4; ++tm)                                           \
        _Pragma("unroll")                                                      \
        for (int tn = 0; tn < 8; ++tn)                                         \
          acc[tm][tn] = __builtin_amdgcn_mfma_f32_16x16x32_bf16(               \
              af[tm], bfr[tn], acc[tm][tn], 0, 0, 0);                          \
      if (t < 15) {                                                            \
        SBAR; /* all waves done reading buffers being overwritten */           \
        VMCNT(8); /* A(t+1) regs ready */                                      \
        writeA(ah, As[c ^ 1], FL, tid);                                        \
        if (t < 14) {                                                          \
          loadA(ah, ASRC, FL, m0, (t + 2) * 32, tid);                          \
          stageB512(BSRC + (t + 2) * 32, Bs[c], lane, wid);                    \
          VMCNT(10); /* B(t+1) landed; B(t+2)+A(t+2) stay in flight */         \
        } else {                                                               \
          VMCNT(0);  /* tail: B(15) landed */                                  \
        }                                                                      \
        LGKMCNT0;                                                              \
        SBAR;                                                                  \
      }                                                                        \
    }                                                                          \
  }

// ============ kernel 1: x = relu(h @ Wfuse + T[cid]) ============
// Full-N block: 64 tokens x 512 cols (h read ONCE chip-wide).  4 waves, each
// 64m x 128n (acc[4][8]).  LDS 72 KB -> 2 blocks/CU.
__global__ __launch_bounds__(256, 2) void k_fuse(
    const void* __restrict__ h, const int* __restrict__ cids,
    const bf16* __restrict__ WfT, const float* __restrict__ Temb,
    const int* __restrict__ flag, bf16* __restrict__ x) {
  __shared__ __align__(16) bf16 As[2][64 * 32];    // 8 KB
  __shared__ __align__(16) bf16 Bs[2][512 * 32];   // 64 KB
  const int tid = threadIdx.x, lane = tid & 63, wid = tid >> 6;
  const int quad = lane >> 4, l15 = lane & 15;
  const size_t m0 = (size_t)blockIdx.x * 64;
  const int fl = *flag;
  const int so = ((quad ^ ((l15 >> 1) & 3)) << 3);  // swizzled read slot

  f32x4 acc[4][8] = {};
  GEMM_PIPE(h, fl, WfT);

  // epilogue: + Temb[cid] bias, relu, bf16 store
#pragma unroll
  for (int tm = 0; tm < 4; ++tm) {
#pragma unroll
    for (int r = 0; r < 4; ++r) {
      const size_t m = m0 + tm * 16 + quad * 4 + r;
      const int c = clip11(cids[m]);
      const float* Trow = Temb + c * 512;
#pragma unroll
      for (int tn = 0; tn < 8; ++tn) {
        const int nn = wid * 128 + tn * 16 + l15;
        x[m * 512 + nn] = (bf16)relu_f(acc[tm][tn][r] + Trow[nn]);
      }
    }
  }
}

// ============ kernel 2: per-token gate logit ============
// Same pipelined skeleton (A = x, always bf16).  WgT 16-col-group interleave:
// col n with (n>>4)&1==0 = tanh side of dim d, ==1 = sigmoid side of same d;
// acc[tm][2p]/[2p+1] in the same lane form the (a,g) pair,
// d = wid*64 + p*16 + l15.
__global__ __launch_bounds__(256, 2) void k_gate1(
    const bf16* __restrict__ x, const bf16* __restrict__ WgT,
    const bf16* __restrict__ canon, float* __restrict__ Apart) {
  __shared__ __align__(16) bf16 As[2][64 * 32];
  __shared__ __align__(16) bf16 Bs[2][512 * 32];
  __shared__ float tok[64];
  const int tid = threadIdx.x, lane = tid & 63, wid = tid >> 6;
  const int quad = lane >> 4, l15 = lane & 15;
  const size_t m0 = (size_t)blockIdx.x * 64;
  const int so = ((quad ^ ((l15 >> 1) & 3)) << 3);

  f32x4 acc[4][8] = {};
  GEMM_PIPE(x, 0, WgT);

  if (tid < 64) tok[tid] = 0.f;
  __syncthreads();
  float bav[4], bbv[4], wcv[4];
#pragma unroll
  for (int p = 0; p < 4; ++p) {
    const int d = wid * 64 + p * 16 + l15;
    bav[p] = (float)canon[CAN_BA1 + d];
    bbv[p] = (float)canon[CAN_BB1 + d];
    wcv[p] = (float)canon[CAN_WC1 + d];
  }
#pragma unroll
  for (int tm = 0; tm < 4; ++tm) {
#pragma unroll
    for (int r = 0; r < 4; ++r) {
      float rs = 0.f;
#pragma unroll
      for (int p = 0; p < 4; ++p) {
        const float a = acc[tm][2 * p][r] + bav[p];
        const float g = acc[tm][2 * p + 1][r] + bbv[p];
        rs += fast_tanh(a) * (1.f / (1.f + __expf(-g))) * wcv[p];
      }
      rs += __shfl_xor(rs, 1, 64);
      rs += __shfl_xor(rs, 2, 64);
      rs += __shfl_xor(rs, 4, 64);
      rs += __shfl_xor(rs, 8, 64);
      if (l15 == 0) atomicAdd(&tok[tm * 16 + quad * 4 + r], rs);
    }
  }
  __syncthreads();
  if (tid < 64) Apart[m0 + tid] = tok[tid];
}

// ============ kernel 3a: per-segment max ============
__global__ __launch_bounds__(256) void k_segmax(
    const float* __restrict__ Apart, const int* __restrict__ cids, unsigned* __restrict__ gmax) {
  __shared__ unsigned sm[88];
  const int tid = threadIdx.x;
  if (tid < 88) sm[tid] = 0u;
  __syncthreads();
  const int base = blockIdx.x * 1024;
  const int b = blockIdx.x >> 4;
#pragma unroll
  for (int it = 0; it < 4; ++it) {
    const int t = base + it * 256 + tid;
    atomicMax(&sm[b * 11 + clip11(cids[t])], fkey(Apart[t]));
  }
  __syncthreads();
  if (tid < 88) atomicMax(&gmax[tid], sm[tid]);
}

// ============ kernel 3b: per-segment sum of exp + counts ============
__global__ __launch_bounds__(256) void k_segsum(
    const float* __restrict__ Apart, const int* __restrict__ cids,
    const unsigned* __restrict__ gmax, float* __restrict__ denom, int* __restrict__ counts) {
  __shared__ float sd[88];
  __shared__ int sc[88];
  const int tid = threadIdx.x;
  if (tid < 88) { sd[tid] = 0.f; sc[tid] = 0; }
  __syncthreads();
  const int base = blockIdx.x * 1024;
  const int b = blockIdx.x >> 4;
#pragma unroll
  for (int it = 0; it < 4; ++it) {
    const int t = base + it * 256 + tid;
    const int seg = b * 11 + clip11(cids[t]);
    atomicAdd(&sd[seg], __expf(Apart[t] - key_to_f(gmax[seg])));
    atomicAdd(&sc[seg], 1);
  }
  __syncthreads();
  if (tid < 88) {
    atomicAdd(&denom[tid], sd[tid]);
    atomicAdd(&counts[tid], sc[tid]);
  }
}

// ============ kernel 3c: cfeat[seg] += w * x[token] (full 512 cols, bf16x2) ============
__global__ __launch_bounds__(256) void k_cfeat(
    const float* __restrict__ Apart, const int* __restrict__ cids,
    const unsigned* __restrict__ gmax, const float* __restrict__ denom,
    const bf16* __restrict__ x, float* __restrict__ cfeat) {
  __shared__ float accf[11 * 512];      // 22.5 KB
  __shared__ float wbuf[512];
  __shared__ unsigned char cbuf[512];
  const int tid = threadIdx.x;
  const int base = blockIdx.x * 512;    // 256 blocks x 512 tokens
  const int b = blockIdx.x >> 5;        // 32 blocks per batch
  for (int i = tid; i < 11 * 512; i += 256) accf[i] = 0.f;
#pragma unroll
  for (int it = 0; it < 2; ++it) {
    const int t = base + it * 256 + tid;
    const int c = clip11(cids[t]);
    const int seg = b * 11 + c;
    wbuf[it * 256 + tid] = __expf(Apart[t] - key_to_f(gmax[seg])) / denom[seg];
    cbuf[it * 256 + tid] = (unsigned char)c;
  }
  __syncthreads();
  const bf16* xp = x + (size_t)base * 512 + tid * 2;
#pragma unroll 4
  for (int i = 0; i < 512; ++i) {
    const float w = wbuf[i];
    const int c = cbuf[i];
    bf16x2 v = *(const bf16x2*)(xp + (size_t)i * 512);
    accf[c * 512 + tid * 2]     += w * (float)v[0];
    accf[c * 512 + tid * 2 + 1] += w * (float)v[1];
  }
  __syncthreads();
  float* cf = cfeat + (size_t)b * 11 * 512;
  for (int i = tid; i < 11 * 512; i += 256)
    atomicAdd(&cf[i], accf[i]);
}

// ============ kernel 4a: cfeat2 = relu(cfeat @ Wintra + b_intra), 88 rows ============
__global__ __launch_bounds__(256) void k_intra(
    const float* __restrict__ cfeat, const bf16* __restrict__ WintraT,
    const bf16* __restrict__ canon, float* __restrict__ cfeat2) {
  __shared__ float row[512];
  const int r = blockIdx.x, tid = threadIdx.x;
  row[tid] = cfeat[(size_t)r * 512 + tid];
  row[tid + 256] = cfeat[(size_t)r * 512 + 256 + tid];
  __syncthreads();
#pragma unroll
  for (int hh = 0; hh < 2; ++hh) {
    const int n = hh * 256 + tid;
    float acc = (float)canon[CAN_BINTRA + n];
    const bf16* wp = WintraT + (size_t)n * 512;
    for (int k = 0; k < 512; k += 8) {
      bf16x8 wv = *(const bf16x8*)(wp + k);
#pragma unroll
      for (int j = 0; j < 8; ++j) acc += row[k + j] * (float)wv[j];
    }
    cfeat2[(size_t)r * 512 + n] = relu_f(acc);
  }
}

__device__ __forceinline__ float block_sum(float v, float* red, int tid) {
#pragma unroll
  for (int off = 32; off > 0; off >>= 1) v += __shfl_xor(v, off, 64);
  __syncthreads();
  if ((tid & 63) == 0) red[tid >> 6] = v;
  __syncthreads();
  return red[0] + red[1] + red[2] + red[3];
}

// ============ kernel 4b: inter-cluster attention + classifier ============
__global__ __launch_bounds__(256) void k_tail(
    const float* __restrict__ cfeat2, const int* __restrict__ counts,
    const bf16* __restrict__ Wa2T, const bf16* __restrict__ Wb2T,
    const bf16* __restrict__ WinterT, const bf16* __restrict__ canon,
    const int* __restrict__ flag, void* __restrict__ out) {
  const int b = blockIdx.x, tid = threadIdx.x;
  __shared__ float row[512];
  __shared__ float A2[11], Wsm[11];
  __shared__ float red[4];
  __shared__ float slide[512];
  __shared__ float hid[256];
  const float* cf = cfeat2 + (size_t)b * 11 * 512;

  for (int c = 0; c < 11; ++c) {
    row[tid] = cf[c * 512 + tid];
    row[tid + 256] = cf[c * 512 + 256 + tid];
    __syncthreads();
    float da = (float)canon[CAN_BA2 + tid], dg = (float)canon[CAN_BB2 + tid];
    const bf16* wa = Wa2T + (size_t)tid * 512;
    const bf16* wb = Wb2T + (size_t)tid * 512;
    for (int k = 0; k < 512; k += 8) {
      bf16x8 av = *(const bf16x8*)(wa + k);
      bf16x8 gv = *(const bf16x8*)(wb + k);
#pragma unroll
      for (int j = 0; j < 8; ++j) {
        const float rv = row[k + j];
        da += rv * (float)av[j];
        dg += rv * (float)gv[j];
      }
    }
    const float contrib = fast_tanh(da) * (1.f / (1.f + __expf(-dg))) * (float)canon[CAN_WC2 + tid];
    const float tot = block_sum(contrib, red, tid);
    if (tid == 0) A2[c] = tot;
    __syncthreads();
  }
  if (tid == 0) {
    float mx = -1e30f;
    for (int c = 0; c < 11; ++c)
      if (counts[b * 11 + c] > 0 && A2[c] > mx) mx = A2[c];
    float s = 0.f;
    for (int c = 0; c < 11; ++c) {
      const float e = (counts[b * 11 + c] > 0) ? __expf(A2[c] - mx) : 0.f;
      Wsm[c] = e; s += e;
    }
    for (int c = 0; c < 11; ++c) Wsm[c] /= s;
  }
  __syncthreads();
  float s0 = 0.f, s1 = 0.f;
  for (int c = 0; c < 11; ++c) {
    const float w = Wsm[c];
    s0 += w * cf[c * 512 + tid];
    s1 += w * cf[c * 512 + 256 + tid];
  }
  slide[tid] = s0; slide[tid + 256] = s1;
  __syncthreads();
  {
    float acc = (float)canon[CAN_BINTER + tid];
    const bf16* wp = WinterT + (size_t)tid * 512;
    for (int k = 0; k < 512; k += 8) {
      bf16x8 wv = *(const bf16x8*)(wp + k);
#pragma unroll
      for (int j = 0; j < 8; ++j) acc += slide[k + j] * (float)wv[j];
    }
    hid[tid] = relu_f(acc);
  }
  __syncthreads();
  const float p0 = hid[tid] * (float)canon[CAN_WCLS + tid * 2 + 0];
  const float p1 = hid[tid] * (float)canon[CAN_WCLS + tid * 2 + 1];
  const float t0 = block_sum(p0, red, tid);
  const float t1 = block_sum(p1, red, tid);
  if (tid == 0) {
    const float o0 = t0 + (float)canon[CAN_BCLS + 0];
    const float o1 = t1 + (float)canon[CAN_BCLS + 1];
    if (*flag) {
      ((float*)out)[b * 2 + 0] = o0;
      ((float*)out)[b * 2 + 1] = o1;
    } else {
      ((bf16*)out)[b * 2 + 0] = (bf16)o0;
      ((bf16*)out)[b * 2 + 1] = (bf16)o1;
    }
  }
}

// ============ prep: transposes + interleaved gate weight + canon + emb-tail ============
__global__ __launch_bounds__(256) void k_prep(
    const void* __restrict__ Wf, const void* __restrict__ bfuse, const void* __restrict__ emb,
    const void* __restrict__ Wa1, const void* __restrict__ Wb1, const void* __restrict__ Wintra,
    const void* __restrict__ Wa2, const void* __restrict__ Wb2, const void* __restrict__ Winter,
    const void* __restrict__ ba1, const void* __restrict__ bb1, const void* __restrict__ wc1,
    const void* __restrict__ bintra, const void* __restrict__ ba2, const void* __restrict__ bb2,
    const void* __restrict__ wc2, const void* __restrict__ binter, const void* __restrict__ Wcls,
    const void* __restrict__ bcls, const int* __restrict__ flag,
    bf16* __restrict__ WfT, bf16* __restrict__ WgT,
    bf16* __restrict__ WintraT, bf16* __restrict__ Wa2T, bf16* __restrict__ Wb2T,
    bf16* __restrict__ WinterT, float* __restrict__ Temb, bf16* __restrict__ canon) {
  const int fl = *flag;
  int id = blockIdx.x * 256 + threadIdx.x;
  if (id < 262144) { WfT[id] = (bf16)cvt(Wf, (id & 511) * 512 + (id >> 9), fl); return; }
  id -= 262144;
  if (id < 262144) {
    // WgT row r (= output col): 16-col-group interleave.
    // q = r>>5 selects d-group, (r>>4)&1 selects side (0=tanh/Wa1, 1=sigmoid/Wb1),
    // d = q*16 + (r&15).
    const int r = id >> 9, k = id & 511;
    const int d = ((r >> 5) << 4) | (r & 15);
    WgT[id] = (bf16)cvt(((r >> 4) & 1) ? Wb1 : Wa1, k * 256 + d, fl);
    return;
  }
  id -= 262144;
  if (id < 262144) { WintraT[id] = (bf16)cvt(Wintra, (id & 511) * 512 + (id >> 9), fl); return; }
  id -= 262144;
  if (id < 131072) { Wa2T[id] = (bf16)cvt(Wa2, (id & 511) * 256 + (id >> 9), fl); return; }
  id -= 131072;
  if (id < 131072) { Wb2T[id] = (bf16)cvt(Wb2, (id & 511) * 256 + (id >> 9), fl); return; }
  id -= 131072;
  if (id < 131072) { WinterT[id] = (bf16)cvt(Winter, (id & 511) * 256 + (id >> 9), fl); return; }
  id -= 131072;
  if (id < 5632) {
    const int c = id >> 9, n = id & 511;
    float s = cvt(bfuse, n, fl);
#pragma unroll
    for (int j = 0; j < 8; ++j) s += cvt(emb, c * 8 + j, fl) * cvt(Wf, (512 + j) * 512 + n, fl);
    Temb[id] = s;
    return;
  }
  id -= 5632;
  if (id < 4096) {
    bf16 v = (bf16)0.0f;
    if (id < 256)        v = (bf16)cvt(ba1, id, fl);
    else if (id < 512)   v = (bf16)cvt(bb1, id - 256, fl);
    else if (id < 768)   v = (bf16)cvt(wc1, id - 512, fl);
    else if (id < 1280)  v = (bf16)cvt(bintra, id - 768, fl);
    else if (id < 1536)  v = (bf16)cvt(ba2, id - 1280, fl);
    else if (id < 1792)  v = (bf16)cvt(bb2, id - 1536, fl);
    else if (id < 2048)  v = (bf16)cvt(wc2, id - 1792, fl);
    else if (id < 2304)  v = (bf16)cvt(binter, id - 2048, fl);
    else if (id < 2816)  v = (bf16)cvt(Wcls, id - 2304, fl);
    else if (id < 2818)  v = (bf16)cvt(bcls, id - 2816, fl);
    canon[id] = v;
  }
}

extern "C" void kernel_launch(void* const* d_in, const int* in_sizes, int n_in,
                              void* d_out, int out_size, void* d_ws, size_t ws_size,
                              hipStream_t stream) {
  (void)in_sizes; (void)n_in; (void)out_size; (void)ws_size;
  const void* h      = d_in[0];
  const int*  cids   = (const int*)d_in[1];
  const void* emb    = d_in[2];
  const void* Wf     = d_in[3];
  const void* bfuse  = d_in[4];
  const void* Wa1    = d_in[5];
  const void* ba1    = d_in[6];
  const void* Wb1    = d_in[7];
  const void* bb1    = d_in[8];
  const void* wc1    = d_in[9];
  const void* Wintra = d_in[11];
  const void* bintra = d_in[12];
  const void* Wa2    = d_in[13];
  const void* ba2    = d_in[14];
  const void* Wb2    = d_in[15];
  const void* bb2    = d_in[16];
  const void* wc2    = d_in[17];
  const void* Winter = d_in[19];
  const void* binter = d_in[20];
  const void* Wcls   = d_in[21];
  const void* bcls   = d_in[22];

  char* ws = (char*)d_ws;
  float*    Apart   = (float*)(ws + OFF_A);
  unsigned* gmax    = (unsigned*)(ws + OFF_SEGMAX);
  float*    denom   = (float*)(ws + OFF_DENOM);
  int*      counts  = (int*)(ws + OFF_CNT);
  float*    cfeat   = (float*)(ws + OFF_CFEAT);
  float*    cfeat2  = (float*)(ws + OFF_CFEAT2);
  int*      flag    = (int*)(ws + OFF_FLAG);
  bf16*     canon   = (bf16*)(ws + OFF_CANON);
  float*    Temb    = (float*)(ws + OFF_TEMB);
  bf16*     x       = (bf16*)(ws + OFF_X);
  bf16*     WfT     = (bf16*)(ws + OFF_WFT);
  bf16*     WgT     = (bf16*)(ws + OFF_WGT);
  bf16*     WintraT = (bf16*)(ws + OFF_WINTRAT);
  bf16*     Wa2T    = (bf16*)(ws + OFF_WA2T);
  bf16*     Wb2T    = (bf16*)(ws + OFF_WB2T);
  bf16*     WinterT = (bf16*)(ws + OFF_WINTERT);

  hipMemsetAsync(d_ws, 0, ZERO_BYTES, stream);
  k_detect<<<1, 64, 0, stream>>>((const unsigned short*)h, flag);
  k_prep<<<4646, 256, 0, stream>>>(Wf, bfuse, emb, Wa1, Wb1, Wintra, Wa2, Wb2, Winter,
                                   ba1, bb1, wc1, bintra, ba2, bb2, wc2, binter, Wcls, bcls,
                                   flag, WfT, WgT, WintraT, Wa2T, Wb2T, WinterT, Temb, canon);
  k_fuse<<<2048, 256, 0, stream>>>(h, cids, WfT, Temb, flag, x);
  k_gate1<<<2048, 256, 0, stream>>>(x, WgT, canon, Apart);
  k_segmax<<<128, 256, 0, stream>>>(Apart, cids, gmax);
  k_segsum<<<128, 256, 0, stream>>>(Apart, cids, gmax, denom, counts);
  k_cfeat<<<256, 256, 0, stream>>>(Apart, cids, gmax, denom, x, cfeat);
  k_intra<<<88, 256, 0, stream>>>(cfeat, WintraT, canon, cfeat2);
  k_tail<<<8, 256, 0, stream>>>(cfeat2, counts, Wa2T, Wb2T, WinterT, canon, flag, d_out);
}

// Round 4
// 720.157 us; speedup vs baseline: 1.2271x; 1.1989x over previous
//
#include <hip/hip_runtime.h>
#include <stdint.h>

typedef __bf16 bf16;
typedef __bf16 bf16x8 __attribute__((ext_vector_type(8)));
typedef __bf16 bf16x4 __attribute__((ext_vector_type(4)));
typedef __bf16 bf16x2 __attribute__((ext_vector_type(2)));
typedef float  f32x4  __attribute__((ext_vector_type(4)));
typedef float  fvec4  __attribute__((ext_vector_type(4)));

// ---------------- workspace layout (bytes) ----------------
static const size_t OFF_A       = 0;         // 131072 f32 (per-token attn logit)
static const size_t OFF_SEGMAX  = 524288;    // 88 u32 (ordered-key max)
static const size_t OFF_DENOM   = 524800;    // 88 f32
static const size_t OFF_CNT     = 525312;    // 88 i32
static const size_t OFF_CFEAT   = 525824;    // 88*512 f32
static const size_t OFF_CFEAT2  = 706048;    // 88*512 f32
static const size_t ZERO_BYTES  = 886272;    // everything above zeroed each call
static const size_t OFF_FLAG    = 886272;    // 64 B (dtype flag)
static const size_t OFF_CANON   = 886336;    // 4096 bf16 canonical small params
static const size_t OFF_TEMB    = 894528;    // [11][512] f32 (emb tail + b_fuse)
static const size_t OFF_X       = 917056;    // 131072*512 bf16 = 128 MiB
static const size_t OFF_WFT     = OFF_X + (size_t)134217728;   // [512][512] bf16
static const size_t OFF_WGT     = OFF_WFT + 524288;            // [512][512] bf16 (Wa1/Wb1 16-col-group interleaved)
static const size_t OFF_WINTRAT = OFF_WGT + 524288;            // [512][512] bf16
static const size_t OFF_WA2T    = OFF_WINTRAT + 524288;        // [256][512] bf16
static const size_t OFF_WB2T    = OFF_WA2T + 262144;
static const size_t OFF_WINTERT = OFF_WB2T + 262144;           // [256][512] bf16
static const size_t OFF_A2V     = OFF_WINTERT + 262144;        // 88 f32 (inter-cluster logits)

// canonical small-param offsets (bf16 elements within CANON)
#define CAN_BA1    0
#define CAN_BB1    256
#define CAN_WC1    512
#define CAN_BINTRA 768
#define CAN_BA2    1280
#define CAN_BB2    1536
#define CAN_WC2    1792
#define CAN_BINTER 2048
#define CAN_WCLS   2304
#define CAN_BCLS   2816

__device__ __forceinline__ int clip11(int c) { return c < 0 ? 0 : (c > 10 ? 10 : c); }

// NaN-PROPAGATING relu
__device__ __forceinline__ float relu_f(float v) { return v < 0.0f ? 0.0f : v; }

// fast tanh via hardware exp: saturates to +/-1, propagates NaN
__device__ __forceinline__ float fast_tanh(float a) {
  return 1.f - 2.f / (1.f + __expf(2.f * a));
}

__device__ __forceinline__ float cvt(const void* p, int i, int fl) {
  return fl ? ((const float*)p)[i] : (float)((const bf16*)p)[i];
}

__device__ __forceinline__ unsigned fkey(float f) {
  unsigned u = __float_as_uint(f);
  return (u & 0x80000000u) ? ~u : (u | 0x80000000u);
}
__device__ __forceinline__ float key_to_f(unsigned k) {
  unsigned u = (k & 0x80000000u) ? (k & 0x7FFFFFFFu) : ~k;
  return __uint_as_float(u);
}

__device__ __forceinline__ void async16(const void* g, void* l) {
  __builtin_amdgcn_global_load_lds(
      (const __attribute__((address_space(1))) unsigned int*)g,
      (__attribute__((address_space(3))) unsigned int*)l, 16, 0, 0);
}

#define VMCNT(n)  asm volatile("s_waitcnt vmcnt(" #n ")" ::: "memory")
#define LGKMCNT0  asm volatile("s_waitcnt lgkmcnt(0)" ::: "memory")
#define SBAR      __builtin_amdgcn_s_barrier()

// ---- GEMM tile: 64 tokens x 512 cols, 256 threads (4 waves), BK=32 ----
// LDS rows are 32 bf16 = 64 B = 4 x 16B slots.  Swizzle: phys slot p of row r
// holds global slot p ^ ((r>>1)&3) (verified: 0 bank conflicts).
// global_load_lds writes linearly -> swizzle applied on the GLOBAL source slot.

// B staging: 512 rows x 32, 8 async16 per thread (counts toward vmcnt).
__device__ __forceinline__ void stageB512(const bf16* __restrict__ src, bf16* lds,
                                          int lane, int wid) {
#pragma unroll
  for (int j = 0; j < 512; j += 64) {
    const int row = j + wid * 16 + (lane >> 2);
    const int gs  = (lane & 3) ^ ((row >> 1) & 3);
    async16(src + (size_t)row * 512 + gs * 8, lds + (j + wid * 16) * 32);
  }
}

// A register-staging: 64 rows x 32 (one bf16 slot of 8 elems per thread).
// Exactly 2 vmem loads per thread for BOTH f32 and bf16 sources (vmcnt parity).
struct AHold { fvec4 v0, v1; bf16x4 b0, b1; };
__device__ __forceinline__ void loadA(AHold& h, const void* __restrict__ src, int fl,
                                      size_t m0, int k0, int tid) {
  const int row = tid >> 2, slot = tid & 3;
  const int gs  = slot ^ ((row >> 1) & 3);
  if (fl) {
    const float* gp = (const float*)src + (m0 + row) * 512 + k0 + gs * 8;
    h.v0 = *(const fvec4*)gp;
    h.v1 = *(const fvec4*)(gp + 4);
  } else {
    const bf16* gp = (const bf16*)src + (m0 + row) * 512 + k0 + gs * 8;
    h.b0 = *(const bf16x4*)gp;
    h.b1 = *(const bf16x4*)(gp + 4);
  }
}
__device__ __forceinline__ void writeA(const AHold& h, bf16* lds, int fl, int tid) {
  const int row = tid >> 2, slot = tid & 3;
  bf16x8 b;
  if (fl) {
    b[0]=(bf16)h.v0[0]; b[1]=(bf16)h.v0[1]; b[2]=(bf16)h.v0[2]; b[3]=(bf16)h.v0[3];
    b[4]=(bf16)h.v1[0]; b[5]=(bf16)h.v1[1]; b[6]=(bf16)h.v1[2]; b[7]=(bf16)h.v1[3];
  } else {
    b[0]=h.b0[0]; b[1]=h.b0[1]; b[2]=h.b0[2]; b[3]=h.b0[3];
    b[4]=h.b1[0]; b[5]=h.b1[1]; b[6]=h.b1[2]; b[7]=h.b1[3];
  }
  *(bf16x8*)(lds + row * 32 + slot * 8) = b;   // linear phys slot (source pre-swizzled)
}

// ============ dtype detector ============
__global__ void k_detect(const unsigned short* __restrict__ hh, int* __restrict__ flag) {
  const int lane = threadIdx.x;  // 64 lanes
  const unsigned short u = hh[lane * 2];
  const int e = (u >> 7) & 0xFF;
  int pl = (e > 96 && e < 140) ? 1 : 0;
#pragma unroll
  for (int off = 1; off < 64; off <<= 1) pl += __shfl_xor(pl, off, 64);
  if (lane == 0) *flag = (pl < 32) ? 1 : 0;
}

// Counted-vmcnt double-buffered K-loop (T4).  Per phase/thread: A=2 loads
// (reg-staged), B=8 global_load_lds.  Steady state keeps 10 vmem in flight
// across the barriers; vmcnt never drains to 0 inside the loop.
// Ledger: barrier_A (post-compute) protects LDS buffers being overwritten;
// vmcnt(8) retires A(t+1) before its ds_write; vmcnt(10) retires B(t+1);
// LGKMCNT0 makes the ds_write visible; barrier_B releases compute(t+1).
#define GEMM_PIPE(ASRC, FL, BSRC)                                              \
  {                                                                            \
    AHold ah;                                                                  \
    loadA(ah, ASRC, FL, m0, 0, tid);                                           \
    stageB512(BSRC, Bs[0], lane, wid);                                         \
    VMCNT(8);                                                                  \
    writeA(ah, As[0], FL, tid);                                                \
    loadA(ah, ASRC, FL, m0, 32, tid);                                          \
    stageB512(BSRC + 32, Bs[1], lane, wid);                                    \
    VMCNT(10);                                                                 \
    LGKMCNT0;                                                                  \
    SBAR;                                                                      \
    for (int t = 0; t < 16; ++t) {                                             \
      const int c = t & 1;                                                     \
      bf16x8 af[4], bfr[8];                                                    \
      _Pragma("unroll")                                                        \
      for (int tt = 0; tt < 4; ++tt)                                           \
        af[tt] = *(const bf16x8*)&As[c][(tt * 16 + l15) * 32 + so];            \
      _Pragma("unroll")                                                        \
      for (int tt = 0; tt < 8; ++tt)                                           \
        bfr[tt] = *(const bf16x8*)&Bs[c][(wid * 128 + tt * 16 + l15) * 32 + so];\
      _Pragma("unroll")                                                        \
      for (int tm = 0; tm < 4; ++tm)                                           \
        _Pragma("unroll")                                                      \
        for (int tn = 0; tn < 8; ++tn)                                         \
          acc[tm][tn] = __builtin_amdgcn_mfma_f32_16x16x32_bf16(               \
              af[tm], bfr[tn], acc[tm][tn], 0, 0, 0);                          \
      if (t < 15) {                                                            \
        SBAR; /* all waves done reading buffers being overwritten */           \
        VMCNT(8); /* A(t+1) regs ready */                                      \
        writeA(ah, As[c ^ 1], FL, tid);                                        \
        if (t < 14) {                                                          \
          loadA(ah, ASRC, FL, m0, (t + 2) * 32, tid);                          \
          stageB512(BSRC + (t + 2) * 32, Bs[c], lane, wid);                    \
          VMCNT(10); /* B(t+1) landed; B(t+2)+A(t+2) stay in flight */         \
        } else {                                                               \
          VMCNT(0);  /* tail: B(15) landed */                                  \
        }                                                                      \
        LGKMCNT0;                                                              \
        SBAR;                                                                  \
      }                                                                        \
    }                                                                          \
  }

// ============ kernel 1: x = relu(h @ Wfuse + T[cid]) ============
// Full-N block: 64 tokens x 512 cols (h read ONCE chip-wide).  4 waves, each
// 64m x 128n (acc[4][8]).  LDS 72 KB -> 2 blocks/CU.
__global__ __launch_bounds__(256, 2) void k_fuse(
    const void* __restrict__ h, const int* __restrict__ cids,
    const bf16* __restrict__ WfT, const float* __restrict__ Temb,
    const int* __restrict__ flag, bf16* __restrict__ x) {
  __shared__ __align__(16) bf16 As[2][64 * 32];    // 8 KB
  __shared__ __align__(16) bf16 Bs[2][512 * 32];   // 64 KB
  const int tid = threadIdx.x, lane = tid & 63, wid = tid >> 6;
  const int quad = lane >> 4, l15 = lane & 15;
  const size_t m0 = (size_t)blockIdx.x * 64;
  const int fl = *flag;
  const int so = ((quad ^ ((l15 >> 1) & 3)) << 3);  // swizzled read slot

  f32x4 acc[4][8] = {};
  GEMM_PIPE(h, fl, WfT);

  // epilogue: + Temb[cid] bias, relu, bf16 store
#pragma unroll
  for (int tm = 0; tm < 4; ++tm) {
#pragma unroll
    for (int r = 0; r < 4; ++r) {
      const size_t m = m0 + tm * 16 + quad * 4 + r;
      const int c = clip11(cids[m]);
      const float* Trow = Temb + c * 512;
#pragma unroll
      for (int tn = 0; tn < 8; ++tn) {
        const int nn = wid * 128 + tn * 16 + l15;
        x[m * 512 + nn] = (bf16)relu_f(acc[tm][tn][r] + Trow[nn]);
      }
    }
  }
}

// ============ kernel 2: per-token gate logit ============
// Same pipelined skeleton (A = x, always bf16).  WgT 16-col-group interleave:
// col n with (n>>4)&1==0 = tanh side of dim d, ==1 = sigmoid side of same d;
// acc[tm][2p]/[2p+1] in the same lane form the (a,g) pair,
// d = wid*64 + p*16 + l15.
__global__ __launch_bounds__(256, 2) void k_gate1(
    const bf16* __restrict__ x, const bf16* __restrict__ WgT,
    const bf16* __restrict__ canon, float* __restrict__ Apart) {
  __shared__ __align__(16) bf16 As[2][64 * 32];
  __shared__ __align__(16) bf16 Bs[2][512 * 32];
  __shared__ float tok[64];
  const int tid = threadIdx.x, lane = tid & 63, wid = tid >> 6;
  const int quad = lane >> 4, l15 = lane & 15;
  const size_t m0 = (size_t)blockIdx.x * 64;
  const int so = ((quad ^ ((l15 >> 1) & 3)) << 3);

  f32x4 acc[4][8] = {};
  GEMM_PIPE(x, 0, WgT);

  if (tid < 64) tok[tid] = 0.f;
  __syncthreads();
  float bav[4], bbv[4], wcv[4];
#pragma unroll
  for (int p = 0; p < 4; ++p) {
    const int d = wid * 64 + p * 16 + l15;
    bav[p] = (float)canon[CAN_BA1 + d];
    bbv[p] = (float)canon[CAN_BB1 + d];
    wcv[p] = (float)canon[CAN_WC1 + d];
  }
#pragma unroll
  for (int tm = 0; tm < 4; ++tm) {
#pragma unroll
    for (int r = 0; r < 4; ++r) {
      float rs = 0.f;
#pragma unroll
      for (int p = 0; p < 4; ++p) {
        const float a = acc[tm][2 * p][r] + bav[p];
        const float g = acc[tm][2 * p + 1][r] + bbv[p];
        rs += fast_tanh(a) * (1.f / (1.f + __expf(-g))) * wcv[p];
      }
      rs += __shfl_xor(rs, 1, 64);
      rs += __shfl_xor(rs, 2, 64);
      rs += __shfl_xor(rs, 4, 64);
      rs += __shfl_xor(rs, 8, 64);
      if (l15 == 0) atomicAdd(&tok[tm * 16 + quad * 4 + r], rs);
    }
  }
  __syncthreads();
  if (tid < 64) Apart[m0 + tid] = tok[tid];
}

// ============ kernel 3a: per-segment max ============
__global__ __launch_bounds__(256) void k_segmax(
    const float* __restrict__ Apart, const int* __restrict__ cids, unsigned* __restrict__ gmax) {
  __shared__ unsigned sm[88];
  const int tid = threadIdx.x;
  if (tid < 88) sm[tid] = 0u;
  __syncthreads();
  const int base = blockIdx.x * 1024;
  const int b = blockIdx.x >> 4;
#pragma unroll
  for (int it = 0; it < 4; ++it) {
    const int t = base + it * 256 + tid;
    atomicMax(&sm[b * 11 + clip11(cids[t])], fkey(Apart[t]));
  }
  __syncthreads();
  if (tid < 88) atomicMax(&gmax[tid], sm[tid]);
}

// ============ kernel 3b: per-segment sum of exp + counts ============
__global__ __launch_bounds__(256) void k_segsum(
    const float* __restrict__ Apart, const int* __restrict__ cids,
    const unsigned* __restrict__ gmax, float* __restrict__ denom, int* __restrict__ counts) {
  __shared__ float sd[88];
  __shared__ int sc[88];
  const int tid = threadIdx.x;
  if (tid < 88) { sd[tid] = 0.f; sc[tid] = 0; }
  __syncthreads();
  const int base = blockIdx.x * 1024;
  const int b = blockIdx.x >> 4;
#pragma unroll
  for (int it = 0; it < 4; ++it) {
    const int t = base + it * 256 + tid;
    const int seg = b * 11 + clip11(cids[t]);
    atomicAdd(&sd[seg], __expf(Apart[t] - key_to_f(gmax[seg])));
    atomicAdd(&sc[seg], 1);
  }
  __syncthreads();
  if (tid < 88) {
    atomicAdd(&denom[tid], sd[tid]);
    atomicAdd(&counts[tid], sc[tid]);
  }
}

// ============ kernel 3c: cfeat[seg] += w * x[token] (full 512 cols, bf16x2) ============
__global__ __launch_bounds__(256) void k_cfeat(
    const float* __restrict__ Apart, const int* __restrict__ cids,
    const unsigned* __restrict__ gmax, const float* __restrict__ denom,
    const bf16* __restrict__ x, float* __restrict__ cfeat) {
  __shared__ float accf[11 * 512];      // 22.5 KB
  __shared__ float wbuf[512];
  __shared__ unsigned char cbuf[512];
  const int tid = threadIdx.x;
  const int base = blockIdx.x * 512;    // 256 blocks x 512 tokens
  const int b = blockIdx.x >> 5;        // 32 blocks per batch
  for (int i = tid; i < 11 * 512; i += 256) accf[i] = 0.f;
#pragma unroll
  for (int it = 0; it < 2; ++it) {
    const int t = base + it * 256 + tid;
    const int c = clip11(cids[t]);
    const int seg = b * 11 + c;
    wbuf[it * 256 + tid] = __expf(Apart[t] - key_to_f(gmax[seg])) / denom[seg];
    cbuf[it * 256 + tid] = (unsigned char)c;
  }
  __syncthreads();
  const bf16* xp = x + (size_t)base * 512 + tid * 2;
#pragma unroll 4
  for (int i = 0; i < 512; ++i) {
    const float w = wbuf[i];
    const int c = cbuf[i];
    bf16x2 v = *(const bf16x2*)(xp + (size_t)i * 512);
    accf[c * 512 + tid * 2]     += w * (float)v[0];
    accf[c * 512 + tid * 2 + 1] += w * (float)v[1];
  }
  __syncthreads();
  float* cf = cfeat + (size_t)b * 11 * 512;
  for (int i = tid; i < 11 * 512; i += 256)
    atomicAdd(&cf[i], accf[i]);
}

__device__ __forceinline__ float block_sum(float v, float* red, int tid) {
#pragma unroll
  for (int off = 32; off > 0; off >>= 1) v += __shfl_xor(v, off, 64);
  __syncthreads();
  if ((tid & 63) == 0) red[tid >> 6] = v;
  __syncthreads();
  return red[0] + red[1] + red[2] + red[3];
}

// ============ kernel 4a: cfeat2 = relu(cfeat @ Wintra + b_intra), 88 rows ============
// FUSED: also computes this row's inter-cluster gate logit A2v[r] (the former
// k_tail phase-1, now 88-way parallel instead of 8-way serial-over-11).
__global__ __launch_bounds__(256) void k_intra(
    const float* __restrict__ cfeat, const bf16* __restrict__ WintraT,
    const bf16* __restrict__ Wa2T, const bf16* __restrict__ Wb2T,
    const bf16* __restrict__ canon, float* __restrict__ cfeat2,
    float* __restrict__ A2v) {
  __shared__ float row[512];
  __shared__ float rowo[512];
  __shared__ float red[4];
  const int r = blockIdx.x, tid = threadIdx.x;
  row[tid] = cfeat[(size_t)r * 512 + tid];
  row[tid + 256] = cfeat[(size_t)r * 512 + 256 + tid];
  __syncthreads();
#pragma unroll
  for (int hh = 0; hh < 2; ++hh) {
    const int n = hh * 256 + tid;
    float acc = (float)canon[CAN_BINTRA + n];
    const bf16* wp = WintraT + (size_t)n * 512;
#pragma unroll 4
    for (int k = 0; k < 512; k += 8) {
      bf16x8 wv = *(const bf16x8*)(wp + k);
#pragma unroll
      for (int j = 0; j < 8; ++j) acc += row[k + j] * (float)wv[j];
    }
    const float v = relu_f(acc);
    cfeat2[(size_t)r * 512 + n] = v;
    rowo[n] = v;
  }
  __syncthreads();
  // inter-cluster gate contribution for this (b,c) row: dim d = tid (256 dims)
  float da = (float)canon[CAN_BA2 + tid], dg = (float)canon[CAN_BB2 + tid];
  const bf16* wa = Wa2T + (size_t)tid * 512;
  const bf16* wb = Wb2T + (size_t)tid * 512;
#pragma unroll 4
  for (int k = 0; k < 512; k += 8) {
    bf16x8 av = *(const bf16x8*)(wa + k);
    bf16x8 gv = *(const bf16x8*)(wb + k);
#pragma unroll
    for (int j = 0; j < 8; ++j) {
      const float rv = rowo[k + j];
      da += rv * (float)av[j];
      dg += rv * (float)gv[j];
    }
  }
  const float contrib = fast_tanh(da) * (1.f / (1.f + __expf(-dg))) * (float)canon[CAN_WC2 + tid];
  const float tot = block_sum(contrib, red, tid);
  if (tid == 0) A2v[r] = tot;
}

// ============ kernel 4b: inter-cluster softmax + slide + classifier ============
__global__ __launch_bounds__(256) void k_tail(
    const float* __restrict__ cfeat2, const float* __restrict__ A2v,
    const int* __restrict__ counts, const bf16* __restrict__ WinterT,
    const bf16* __restrict__ canon, const int* __restrict__ flag,
    void* __restrict__ out) {
  const int b = blockIdx.x, tid = threadIdx.x;
  __shared__ float Wsm[11];
  __shared__ float red[4];
  __shared__ float slide[512];
  __shared__ float hid[256];
  const float* cf = cfeat2 + (size_t)b * 11 * 512;

  if (tid == 0) {
    float mx = -1e30f;
    for (int c = 0; c < 11; ++c)
      if (counts[b * 11 + c] > 0 && A2v[b * 11 + c] > mx) mx = A2v[b * 11 + c];
    float s = 0.f;
    for (int c = 0; c < 11; ++c) {
      const float e = (counts[b * 11 + c] > 0) ? __expf(A2v[b * 11 + c] - mx) : 0.f;
      Wsm[c] = e; s += e;
    }
    for (int c = 0; c < 11; ++c) Wsm[c] /= s;
  }
  __syncthreads();
  float s0 = 0.f, s1 = 0.f;
#pragma unroll
  for (int c = 0; c < 11; ++c) {
    const float w = Wsm[c];
    s0 += w * cf[c * 512 + tid];
    s1 += w * cf[c * 512 + 256 + tid];
  }
  slide[tid] = s0; slide[tid + 256] = s1;
  __syncthreads();
  {
    float acc = (float)canon[CAN_BINTER + tid];
    const bf16* wp = WinterT + (size_t)tid * 512;
#pragma unroll 4
    for (int k = 0; k < 512; k += 8) {
      bf16x8 wv = *(const bf16x8*)(wp + k);
#pragma unroll
      for (int j = 0; j < 8; ++j) acc += slide[k + j] * (float)wv[j];
    }
    hid[tid] = relu_f(acc);
  }
  __syncthreads();
  const float p0 = hid[tid] * (float)canon[CAN_WCLS + tid * 2 + 0];
  const float p1 = hid[tid] * (float)canon[CAN_WCLS + tid * 2 + 1];
  const float t0 = block_sum(p0, red, tid);
  const float t1 = block_sum(p1, red, tid);
  if (tid == 0) {
    const float o0 = t0 + (float)canon[CAN_BCLS + 0];
    const float o1 = t1 + (float)canon[CAN_BCLS + 1];
    if (*flag) {
      ((float*)out)[b * 2 + 0] = o0;
      ((float*)out)[b * 2 + 1] = o1;
    } else {
      ((bf16*)out)[b * 2 + 0] = (bf16)o0;
      ((bf16*)out)[b * 2 + 1] = (bf16)o1;
    }
  }
}

// ============ prep: transposes + interleaved gate weight + canon + emb-tail ============
__global__ __launch_bounds__(256) void k_prep(
    const void* __restrict__ Wf, const void* __restrict__ bfuse, const void* __restrict__ emb,
    const void* __restrict__ Wa1, const void* __restrict__ Wb1, const void* __restrict__ Wintra,
    const void* __restrict__ Wa2, const void* __restrict__ Wb2, const void* __restrict__ Winter,
    const void* __restrict__ ba1, const void* __restrict__ bb1, const void* __restrict__ wc1,
    const void* __restrict__ bintra, const void* __restrict__ ba2, const void* __restrict__ bb2,
    const void* __restrict__ wc2, const void* __restrict__ binter, const void* __restrict__ Wcls,
    const void* __restrict__ bcls, const int* __restrict__ flag,
    bf16* __restrict__ WfT, bf16* __restrict__ WgT,
    bf16* __restrict__ WintraT, bf16* __restrict__ Wa2T, bf16* __restrict__ Wb2T,
    bf16* __restrict__ WinterT, float* __restrict__ Temb, bf16* __restrict__ canon) {
  const int fl = *flag;
  int id = blockIdx.x * 256 + threadIdx.x;
  if (id < 262144) { WfT[id] = (bf16)cvt(Wf, (id & 511) * 512 + (id >> 9), fl); return; }
  id -= 262144;
  if (id < 262144) {
    // WgT row r (= output col): 16-col-group interleave.
    // q = r>>5 selects d-group, (r>>4)&1 selects side (0=tanh/Wa1, 1=sigmoid/Wb1),
    // d = q*16 + (r&15).
    const int r = id >> 9, k = id & 511;
    const int d = ((r >> 5) << 4) | (r & 15);
    WgT[id] = (bf16)cvt(((r >> 4) & 1) ? Wb1 : Wa1, k * 256 + d, fl);
    return;
  }
  id -= 262144;
  if (id < 262144) { WintraT[id] = (bf16)cvt(Wintra, (id & 511) * 512 + (id >> 9), fl); return; }
  id -= 262144;
  if (id < 131072) { Wa2T[id] = (bf16)cvt(Wa2, (id & 511) * 256 + (id >> 9), fl); return; }
  id -= 131072;
  if (id < 131072) { Wb2T[id] = (bf16)cvt(Wb2, (id & 511) * 256 + (id >> 9), fl); return; }
  id -= 131072;
  if (id < 131072) { WinterT[id] = (bf16)cvt(Winter, (id & 511) * 256 + (id >> 9), fl); return; }
  id -= 131072;
  if (id < 5632) {
    const int c = id >> 9, n = id & 511;
    float s = cvt(bfuse, n, fl);
#pragma unroll
    for (int j = 0; j < 8; ++j) s += cvt(emb, c * 8 + j, fl) * cvt(Wf, (512 + j) * 512 + n, fl);
    Temb[id] = s;
    return;
  }
  id -= 5632;
  if (id < 4096) {
    bf16 v = (bf16)0.0f;
    if (id < 256)        v = (bf16)cvt(ba1, id, fl);
    else if (id < 512)   v = (bf16)cvt(bb1, id - 256, fl);
    else if (id < 768)   v = (bf16)cvt(wc1, id - 512, fl);
    else if (id < 1280)  v = (bf16)cvt(bintra, id - 768, fl);
    else if (id < 1536)  v = (bf16)cvt(ba2, id - 1280, fl);
    else if (id < 1792)  v = (bf16)cvt(bb2, id - 1536, fl);
    else if (id < 2048)  v = (bf16)cvt(wc2, id - 1792, fl);
    else if (id < 2304)  v = (bf16)cvt(binter, id - 2048, fl);
    else if (id < 2816)  v = (bf16)cvt(Wcls, id - 2304, fl);
    else if (id < 2818)  v = (bf16)cvt(bcls, id - 2816, fl);
    canon[id] = v;
  }
}

extern "C" void kernel_launch(void* const* d_in, const int* in_sizes, int n_in,
                              void* d_out, int out_size, void* d_ws, size_t ws_size,
                              hipStream_t stream) {
  (void)in_sizes; (void)n_in; (void)out_size; (void)ws_size;
  const void* h      = d_in[0];
  const int*  cids   = (const int*)d_in[1];
  const void* emb    = d_in[2];
  const void* Wf     = d_in[3];
  const void* bfuse  = d_in[4];
  const void* Wa1    = d_in[5];
  const void* ba1    = d_in[6];
  const void* Wb1    = d_in[7];
  const void* bb1    = d_in[8];
  const void* wc1    = d_in[9];
  const void* Wintra = d_in[11];
  const void* bintra = d_in[12];
  const void* Wa2    = d_in[13];
  const void* ba2    = d_in[14];
  const void* Wb2    = d_in[15];
  const void* bb2    = d_in[16];
  const void* wc2    = d_in[17];
  const void* Winter = d_in[19];
  const void* binter = d_in[20];
  const void* Wcls   = d_in[21];
  const void* bcls   = d_in[22];

  char* ws = (char*)d_ws;
  float*    Apart   = (float*)(ws + OFF_A);
  unsigned* gmax    = (unsigned*)(ws + OFF_SEGMAX);
  float*    denom   = (float*)(ws + OFF_DENOM);
  int*      counts  = (int*)(ws + OFF_CNT);
  float*    cfeat   = (float*)(ws + OFF_CFEAT);
  float*    cfeat2  = (float*)(ws + OFF_CFEAT2);
  int*      flag    = (int*)(ws + OFF_FLAG);
  bf16*     canon   = (bf16*)(ws + OFF_CANON);
  float*    Temb    = (float*)(ws + OFF_TEMB);
  bf16*     x       = (bf16*)(ws + OFF_X);
  bf16*     WfT     = (bf16*)(ws + OFF_WFT);
  bf16*     WgT     = (bf16*)(ws + OFF_WGT);
  bf16*     WintraT = (bf16*)(ws + OFF_WINTRAT);
  bf16*     Wa2T    = (bf16*)(ws + OFF_WA2T);
  bf16*     Wb2T    = (bf16*)(ws + OFF_WB2T);
  bf16*     WinterT = (bf16*)(ws + OFF_WINTERT);
  float*    A2v     = (float*)(ws + OFF_A2V);

  hipMemsetAsync(d_ws, 0, ZERO_BYTES, stream);
  k_detect<<<1, 64, 0, stream>>>((const unsigned short*)h, flag);
  k_prep<<<4646, 256, 0, stream>>>(Wf, bfuse, emb, Wa1, Wb1, Wintra, Wa2, Wb2, Winter,
                                   ba1, bb1, wc1, bintra, ba2, bb2, wc2, binter, Wcls, bcls,
                                   flag, WfT, WgT, WintraT, Wa2T, Wb2T, WinterT, Temb, canon);
  k_fuse<<<2048, 256, 0, stream>>>(h, cids, WfT, Temb, flag, x);
  k_gate1<<<2048, 256, 0, stream>>>(x, WgT, canon, Apart);
  k_segmax<<<128, 256, 0, stream>>>(Apart, cids, gmax);
  k_segsum<<<128, 256, 0, stream>>>(Apart, cids, gmax, denom, counts);
  k_cfeat<<<256, 256, 0, stream>>>(Apart, cids, gmax, denom, x, cfeat);
  k_intra<<<88, 256, 0, stream>>>(cfeat, WintraT, Wa2T, Wb2T, canon, cfeat2, A2v);
  k_tail<<<8, 256, 0, stream>>>(cfeat2, A2v, counts, WinterT, canon, flag, d_out);
}